// Round 14
// baseline (168.797 us; speedup 1.0000x reference)
//
#include <hip/hip_runtime.h>

#define N_NODES 50000
#define N_EDGES 800000
#define D_IN 128
#define D_OUT 128
#define N_TYPES 4
#define LN_EPS 1e-5f
#define N_BUCKETS (N_TYPES * N_NODES)   // 200000, keyed as node*4+type
#define NJT 9                            // 8 w1 halves + 1 self (self slab feeds gemm2)

// binned (col,type) sort
#define NBIN 196                          // col >> 8  (256 nodes per bin)
#define BIN_CAP 8192                      // mean 4096/bin, ~64 sigma headroom
#define TILE_A 2048
#define NBA ((N_EDGES + TILE_A - 1) / TILE_A)   // 391

typedef __attribute__((ext_vector_type(4))) float f32x4;
typedef __attribute__((ext_vector_type(8))) __bf16 bf16x8;
typedef __attribute__((ext_vector_type(8))) unsigned short u16x8;

// ---- workspace layout (bytes), 256-aligned sections ----
constexpr size_t wsal(size_t x) { return (x + 255) & ~size_t(255); }
constexpr size_t OFF_PTR    = 0;                                              // (200001)*4
constexpr size_t OFF_BCUR   = OFF_PTR   + wsal((size_t)(N_BUCKETS + 1) * 4);  // 256*4
constexpr size_t OFF_BINBUF = OFF_BCUR  + wsal((size_t)256 * 4);              // 196*8192*4 = 6.4MB
constexpr size_t OFF_SROWS  = OFF_BINBUF + wsal((size_t)NBIN * BIN_CAP * 4);  // 800000*4
constexpr size_t OFF_XB     = OFF_SROWS + wsal((size_t)N_EDGES * 4);          // 12.8MB
constexpr size_t OFF_WCAT   = OFF_XB    + wsal((size_t)N_NODES * D_IN * 2);
constexpr size_t OFF_BIAS   = OFF_WCAT  + wsal((size_t)NJT * 4 * 128 * 32 * 2);
constexpr size_t OFF_W2T    = OFF_BIAS  + wsal((size_t)NJT * 128 * 4);
constexpr size_t OFF_XAB    = OFF_W2T   + wsal((size_t)N_TYPES * 4 * 128 * 32 * 2);
constexpr size_t OFF_S      = OFF_XAB   + wsal((size_t)8 * N_NODES * 128 * 2);   // 102.4MB
constexpr size_t WS_TOTAL   = OFF_S     + wsal((size_t)N_BUCKETS * 128 * 2);     // +51.2MB ≈ 178MB

__device__ __forceinline__ unsigned short f2bf(float f) {
    unsigned int u = __builtin_bit_cast(unsigned int, f);
    u += 0x7FFFu + ((u >> 16) & 1u);   // RNE; inputs finite
    return (unsigned short)(u >> 16);
}
__device__ __forceinline__ float bf2f_lo(unsigned int u) { return __builtin_bit_cast(float, u << 16); }
__device__ __forceinline__ float bf2f_hi(unsigned int u) { return __builtin_bit_cast(float, u & 0xFFFF0000u); }

// ---------------- merged prep: x->bf16 | weight transposes ----------------
#define PREP_N0 (NJT * 4 * 128 * 32)
#define PREP_N1 (NJT * 128)
#define PREP_N2 (N_TYPES * 4 * 128 * 32)
#define NB_CVT  (N_NODES * D_IN / 4 / 256)                       // 6250 (exact)
#define NB_PREP ((PREP_N0 + PREP_N1 + PREP_N2 + 255) / 256)      // 837

__global__ __launch_bounds__(256) void k_prep_all(
    const float* __restrict__ x,
    const float* __restrict__ w1, const float* __restrict__ sw,
    const float* __restrict__ b1, const float* __restrict__ sb,
    const float* __restrict__ w2,
    unsigned short* __restrict__ xb,
    unsigned short* __restrict__ wcatT, float* __restrict__ bias,
    unsigned short* __restrict__ w2T)
{
    const int bx = blockIdx.x;
    const int tid = threadIdx.x;
    if (bx < NB_CVT) {
        int i = bx * 256 + tid;
        const float4 v = reinterpret_cast<const float4*>(x)[i];
        ushort4 o;
        o.x = f2bf(v.x); o.y = f2bf(v.y); o.z = f2bf(v.z); o.w = f2bf(v.w);
        reinterpret_cast<ushort4*>(xb)[i] = o;
        return;
    }
    int gid = (bx - NB_CVT) * 256 + tid;
    if (gid < PREP_N0) {
        // wcatT[jt][ks][jm][kk] = Wcat[ks*32+kk][jt*128+jm]
        int kk = gid & 31;
        int jm = (gid >> 5) & 127;
        int ks = (gid >> 12) & 3;
        int jt = gid >> 14;
        int k  = ks * 32 + kk;
        float v;
        if (jt < 8) {
            int t = jt >> 1, half = jt & 1;
            v = w1[((size_t)t * 256 + half * 128 + k) * 128 + jm];
        } else {
            v = sw[(size_t)k * 128 + jm];
        }
        wcatT[gid] = f2bf(v);
        return;
    }
    gid -= PREP_N0;
    if (gid < PREP_N1) {
        int jt = gid >> 7, jm = gid & 127;
        float v = 0.f;
        if (jt < 8) { if (jt & 1) v = b1[(jt >> 1) * 128 + jm]; }
        else v = sb[jm];
        bias[gid] = v;
        return;
    }
    gid -= PREP_N1;
    if (gid < PREP_N2) {
        // w2T[t][ks][f][kk] = w2[t][ks*32+kk][f]
        int kk = gid & 31;
        int f  = (gid >> 5) & 127;
        int ks = (gid >> 12) & 3;
        int t  = gid >> 14;
        float v = w2[((size_t)t * 128 + ks * 32 + kk) * 128 + f];
        w2T[gid] = f2bf(v);
    }
}

// ---------------- binned (col,type) sort, pass A ----------------
// record = c_local[8] << 21 | t[2] << 19 | absrow[19], absrow = 2t*N + srcRow < 350000 < 2^19
__global__ __launch_bounds__(256) void k_binA(
    const int* __restrict__ ei, const int* __restrict__ attr,
    int* __restrict__ binCur, unsigned int* __restrict__ binBuf)
{
    __shared__ int hist[NBIN];
    __shared__ int base[NBIN];
    const int tid = threadIdx.x;
    const int e0 = blockIdx.x * TILE_A;
    if (tid < NBIN) hist[tid] = 0;
    __syncthreads();
    #pragma unroll
    for (int it = 0; it < TILE_A / 256; ++it) {
        int e = e0 + it * 256 + tid;
        if (e < N_EDGES) atomicAdd(&hist[ei[N_EDGES + e] >> 8], 1);
    }
    __syncthreads();
    if (tid < NBIN) {
        base[tid] = atomicAdd(&binCur[tid], hist[tid]);
        hist[tid] = 0;   // reuse as local rank counter
    }
    __syncthreads();
    #pragma unroll
    for (int it = 0; it < TILE_A / 256; ++it) {
        int e = e0 + it * 256 + tid;
        if (e < N_EDGES) {
            int c = ei[N_EDGES + e];
            int t = attr[e];
            int row = ei[e];
            int bin = c >> 8;
            int lr = atomicAdd(&hist[bin], 1);
            int dst = base[bin] + lr;
            unsigned int rec = ((unsigned int)(c & 255) << 21) | ((unsigned int)t << 19)
                             | (unsigned int)(2 * t * N_NODES + row);
            if (dst < BIN_CAP) binBuf[(size_t)bin * BIN_CAP + dst] = rec;
        }
    }
}

// ---------------- pass B: per-bin LDS counting sort -> ptr + srows (all coalesced) ----------------
__global__ __launch_bounds__(256) void k_binB(
    const unsigned int* __restrict__ binBuf, const int* __restrict__ binCur,
    int* __restrict__ ptr, int* __restrict__ srows)
{
    __shared__ unsigned int recs[BIN_CAP];   // 32KB
    __shared__ int stage[BIN_CAP];           // 32KB
    __shared__ int boff[1024];               // bucket excl offsets, then cursors (4KB)
    __shared__ int sred[256];
    const int b = blockIdx.x, tid = threadIdx.x;
    const int cntb = min(binCur[b], BIN_CAP);

    for (int i = tid; i < cntb; i += 256)
        recs[i] = binBuf[(size_t)b * BIN_CAP + i];

    // binBase = sum of binCur over bins < b (redundant tree-reduce per block)
    int myv = (tid < NBIN && tid < b) ? binCur[tid] : 0;
    sred[tid] = myv;
    __syncthreads();
    #pragma unroll
    for (int d = 128; d > 0; d >>= 1) {
        if (tid < d) sred[tid] += sred[tid + d];
        __syncthreads();
    }
    const int binBase = sred[0];
    __syncthreads();

    // bucket histogram (key = clocal*4 + t, matches global bucket order)
    for (int k = tid; k < 1024; k += 256) boff[k] = 0;
    __syncthreads();
    for (int i = tid; i < cntb; i += 256)
        atomicAdd(&boff[(recs[i] >> 19) & 1023], 1);
    __syncthreads();

    // exclusive scan of the 1024 counts (each thread owns 4)
    const int c0 = boff[tid * 4], c1 = boff[tid * 4 + 1], c2 = boff[tid * 4 + 2], c3 = boff[tid * 4 + 3];
    const int ts = c0 + c1 + c2 + c3;
    sred[tid] = ts;
    __syncthreads();
    #pragma unroll
    for (int d = 1; d < 256; d <<= 1) {
        int add = (tid >= d) ? sred[tid - d] : 0;
        __syncthreads();
        sred[tid] += add;
        __syncthreads();
    }
    const int run = sred[tid] - ts;
    const int o0 = run, o1 = run + c0, o2 = run + c0 + c1, o3 = run + c0 + c1 + c2;
    boff[tid * 4 + 0] = o0; boff[tid * 4 + 1] = o1;
    boff[tid * 4 + 2] = o2; boff[tid * 4 + 3] = o3;
    // ptr for this bin's buckets (contiguous 4KB)
    const int gb = b * 1024 + tid * 4;
    if (gb + 3 < N_BUCKETS) {
        int4 pv; pv.x = binBase + o0; pv.y = binBase + o1; pv.z = binBase + o2; pv.w = binBase + o3;
        *reinterpret_cast<int4*>(ptr + gb) = pv;
    } else {
        if (gb + 0 < N_BUCKETS) ptr[gb + 0] = binBase + o0;
        if (gb + 1 < N_BUCKETS) ptr[gb + 1] = binBase + o1;
        if (gb + 2 < N_BUCKETS) ptr[gb + 2] = binBase + o2;
        if (gb + 3 < N_BUCKETS) ptr[gb + 3] = binBase + o3;
    }
    if (b == 0 && tid == 0) ptr[N_BUCKETS] = N_EDGES;
    __syncthreads();

    // scatter into LDS stage (boff now acts as cursor)
    for (int i = tid; i < cntb; i += 256) {
        unsigned int r = recs[i];
        int pos = atomicAdd(&boff[(r >> 19) & 1023], 1);
        stage[pos] = (int)(r & 0x7FFFFu);
    }
    __syncthreads();
    // stream out fully coalesced
    for (int i = tid; i < cntb; i += 256)
        srows[binBase + i] = stage[i];
}

// ---------------- GEMM1: x-tile staged ONCE; weight slabs register-prefetched (T14) ----------------
// Per jt: {barrier-protected ds_write of slab jt (already in regs)} -> issue slab jt+1 loads ->
// barrier -> 16 MFMA + direct-global epilogue -> barrier. Load latency hides under MFMA/epilogue.
__global__ __launch_bounds__(256, 2) void k_gemm1(
    const unsigned short* __restrict__ xb,
    const unsigned short* __restrict__ wcatT,
    const float* __restrict__ bias,
    unsigned short* __restrict__ xab)
{
    const int nb = blockIdx.x * 128;

    __shared__ __align__(16) unsigned short sX[128 * 136];  // x rows [n][k], staged once
    __shared__ __align__(16) unsigned short sW[128 * 136];  // weight slab [f][ks*32+kk]

    const int tid = threadIdx.x;
    const int lane = tid & 63;
    const int w = tid >> 6;
    const int g = lane >> 4;
    const int c = lane & 15;
    const int wf = w >> 1;   // j half
    const int we = w & 1;    // n half

    #pragma unroll
    for (int it = 0; it < 8; ++it) {
        int row = 16 * it + (tid >> 4);
        int node = min(nb + row, N_NODES - 1);
        const u16x8 v = *reinterpret_cast<const u16x8*>(xb + (size_t)node * D_IN + (tid & 15) * 8);
        *reinterpret_cast<u16x8*>(&sX[row * 136 + (tid & 15) * 8]) = v;
    }

    // prologue: slab 0 into registers
    u16x8 wreg[8];
    {
        const u16x8* gsrc = reinterpret_cast<const u16x8*>(wcatT);
        #pragma unroll
        for (int i = 0; i < 8; ++i) wreg[i] = gsrc[i * 256 + tid];
    }

    for (int jt = 0; jt < 8; ++jt) {
        // ds_write slab jt: global [ks][f][kk] order -> LDS [f][136]
        #pragma unroll
        for (int i = 0; i < 8; ++i) {
            int idx = i * 256 + tid;
            int ks = idx >> 9, f = (idx >> 2) & 127, k8 = idx & 3;
            *reinterpret_cast<u16x8*>(&sW[f * 136 + ks * 32 + k8 * 8]) = wreg[i];
        }
        // issue next slab's loads now; they complete under this jt's MFMA + epilogue
        if (jt < 7) {
            const u16x8* gsrc = reinterpret_cast<const u16x8*>(wcatT + (size_t)(jt + 1) * 16384);
            #pragma unroll
            for (int i = 0; i < 8; ++i) wreg[i] = gsrc[i * 256 + tid];
        }
        __syncthreads();   // sW (and sX on jt=0) visible

        f32x4 acc[4][4];
        #pragma unroll
        for (int ft = 0; ft < 4; ++ft)
            #pragma unroll
            for (int et = 0; et < 4; ++et)
                acc[ft][et] = f32x4{0.f, 0.f, 0.f, 0.f};

        #pragma unroll
        for (int ks = 0; ks < 4; ++ks) {
            bf16x8 af[4], bfr[4];
            #pragma unroll
            for (int ft = 0; ft < 4; ++ft)
                af[ft] = *reinterpret_cast<const bf16x8*>(&sW[(64 * wf + 16 * ft + c) * 136 + ks * 32 + 8 * g]);
            #pragma unroll
            for (int et = 0; et < 4; ++et)
                bfr[et] = *reinterpret_cast<const bf16x8*>(&sX[(64 * we + 16 * et + c) * 136 + ks * 32 + 8 * g]);
            #pragma unroll
            for (int ft = 0; ft < 4; ++ft)
                #pragma unroll
                for (int et = 0; et < 4; ++et)
                    acc[ft][et] = __builtin_amdgcn_mfma_f32_16x16x32_bf16(af[ft], bfr[et], acc[ft][et], 0, 0, 0);
        }

        // epilogue: +bias, pack, write direct to global (wave-local rows -> lines merge in L2)
        float bv[4][4];
        #pragma unroll
        for (int ft = 0; ft < 4; ++ft)
            #pragma unroll
            for (int r = 0; r < 4; ++r)
                bv[ft][r] = bias[jt * 128 + 64 * wf + 16 * ft + 4 * g + r];
        #pragma unroll
        for (int et = 0; et < 4; ++et) {
            int n = 64 * we + 16 * et + c;
            int node = nb + n;
            if (node < N_NODES) {
                unsigned int* orow = reinterpret_cast<unsigned int*>(
                    xab + ((size_t)jt * N_NODES + node) * 128);
                #pragma unroll
                for (int ft = 0; ft < 4; ++ft) {
                    int f0 = 64 * wf + 16 * ft + 4 * g;
                    uint2 pk;
                    pk.x = (unsigned int)f2bf(acc[ft][et][0] + bv[ft][0])
                         | ((unsigned int)f2bf(acc[ft][et][1] + bv[ft][1]) << 16);
                    pk.y = (unsigned int)f2bf(acc[ft][et][2] + bv[ft][2])
                         | ((unsigned int)f2bf(acc[ft][et][3] + bv[ft][3]) << 16);
                    *reinterpret_cast<uint2*>(orow + (f0 >> 1)) = pk;
                }
            }
        }
        __syncthreads();   // MFMA reads of sW done before next jt's ds_write
    }
}

// ---------------- node-major aggregation: one wave per node, scalar control plane ----------------
// One coalesced chunk load of <=64 edge rows per node, then per-edge v_readlane (no per-edge VMEM).
__global__ __launch_bounds__(256) void k_agg(const unsigned short* __restrict__ xab,
                                             const int* __restrict__ ptr,
                                             const int* __restrict__ srows,
                                             unsigned short* __restrict__ S)
{
    const int n = (blockIdx.x * 256 + threadIdx.x) >> 6;   // node = global wave id
    if (n >= N_NODES) return;
    const int lane = threadIdx.x & 63;
    const unsigned int* x32 = reinterpret_cast<const unsigned int*>(xab);

    int seg[5];
    #pragma unroll
    for (int t = 0; t < 5; ++t)
        seg[t] = __builtin_amdgcn_readfirstlane(ptr[4 * n + t]);

    float xbl[4], xbh[4];
    #pragma unroll
    for (int t = 0; t < 4; ++t) {
        unsigned int v = x32[((size_t)(2 * t + 1) * N_NODES + n) * 64 + lane];
        xbl[t] = bf2f_lo(v); xbh[t] = bf2f_hi(v);
    }

    float al[4] = {0.f, 0.f, 0.f, 0.f}, ah[4] = {0.f, 0.f, 0.f, 0.f};

    const int p0 = seg[0], pE = seg[4];
    for (int co = p0; co < pE; co += 64) {
        const int rem = pE - co;
        const int cv = srows[co + min(lane, rem - 1)];   // one coalesced load covers the chunk
        const int ce = min(co + 64, pE);
        #pragma unroll
        for (int t = 0; t < 4; ++t) {
            const int lo = max(seg[t], co);
            const int hi = min(seg[t + 1], ce);
            int j = lo;
            for (; j + 4 <= hi; j += 4) {
                int a0 = __builtin_amdgcn_readlane(cv, j - co);
                int a1 = __builtin_amdgcn_readlane(cv, j + 1 - co);
                int a2 = __builtin_amdgcn_readlane(cv, j + 2 - co);
                int a3 = __builtin_amdgcn_readlane(cv, j + 3 - co);
                unsigned int v0 = x32[(size_t)a0 * 64 + lane];
                unsigned int v1 = x32[(size_t)a1 * 64 + lane];
                unsigned int v2 = x32[(size_t)a2 * 64 + lane];
                unsigned int v3 = x32[(size_t)a3 * 64 + lane];
                al[t] += fmaxf(bf2f_lo(v0) + xbl[t], 0.f) + fmaxf(bf2f_lo(v1) + xbl[t], 0.f)
                       + fmaxf(bf2f_lo(v2) + xbl[t], 0.f) + fmaxf(bf2f_lo(v3) + xbl[t], 0.f);
                ah[t] += fmaxf(bf2f_hi(v0) + xbh[t], 0.f) + fmaxf(bf2f_hi(v1) + xbh[t], 0.f)
                       + fmaxf(bf2f_hi(v2) + xbh[t], 0.f) + fmaxf(bf2f_hi(v3) + xbh[t], 0.f);
            }
            for (; j < hi; ++j) {
                int a = __builtin_amdgcn_readlane(cv, j - co);
                unsigned int v = x32[(size_t)a * 64 + lane];
                al[t] += fmaxf(bf2f_lo(v) + xbl[t], 0.f);
                ah[t] += fmaxf(bf2f_hi(v) + xbh[t], 0.f);
            }
        }
    }

    unsigned int* S32 = reinterpret_cast<unsigned int*>(S);
    #pragma unroll
    for (int t = 0; t < 4; ++t)
        S32[((size_t)n * 4 + t) * 64 + lane] =
            (unsigned int)f2bf(al[t]) | ((unsigned int)f2bf(ah[t]) << 16);
}

// ---------------- GEMM2 (+self-proj) + ReLU + LayerNorm fused, register-prefetched staging ----------------
__global__ __launch_bounds__(256, 2) void k_gemm2_ln(
    const unsigned short* __restrict__ S,      // node-major [n][4][128]
    const unsigned short* __restrict__ w2T,
    const unsigned short* __restrict__ wcatT,   // slab 8 = self weights
    const unsigned short* __restrict__ xb,
    const float* __restrict__ b2,
    const float* __restrict__ sb,
    const int* __restrict__ ptr,                // counts via diffs
    const float* __restrict__ gamma,
    const float* __restrict__ beta,
    float* __restrict__ out)
{
    const int nb = blockIdx.x * 128;
    __shared__ __align__(16) unsigned char sm[128 * 136 * 2 + 4 * 128 * 32 * 2 + 512 * 4];
    unsigned short* sS  = reinterpret_cast<unsigned short*>(sm);               // [128*136]
    unsigned short* sW2 = reinterpret_cast<unsigned short*>(sm + 34816);       // [4*128*32]
    float* sB2          = reinterpret_cast<float*>(sm + 34816 + 32768);        // [512]
    float* rows         = reinterpret_cast<float*>(sm);                        // [128][132] alias, post-MFMA

    const int tid = threadIdx.x;
    const int lane = tid & 63;
    const int w = tid >> 6;
    const int g = lane >> 4;
    const int c = lane & 15;
    const int wf = w >> 1;   // f half
    const int we = w & 1;    // n half

    sB2[tid] = b2[tid];
    sB2[tid + 256] = b2[tid + 256];

    f32x4 acc[4][4];
    #pragma unroll
    for (int ft = 0; ft < 4; ++ft)
        #pragma unroll
        for (int et = 0; et < 4; ++et)
            acc[ft][et] = f32x4{0.f, 0.f, 0.f, 0.f};

    // prologue: phase-0 sources into registers
    u16x8 sreg[8], wreg[8];
    {
        #pragma unroll
        for (int it = 0; it < 8; ++it) {
            int row = 16 * it + (tid >> 4);
            int node = min(nb + row, N_NODES - 1);
            sreg[it] = *reinterpret_cast<const u16x8*>(S + ((size_t)node * 4 + 0) * 128 + (tid & 15) * 8);
        }
        const u16x8* gsrc = reinterpret_cast<const u16x8*>(w2T);
        #pragma unroll
        for (int it = 0; it < 8; ++it)
            wreg[it] = gsrc[it * 256 + tid];
    }

    for (int t = 0; t < 5; ++t) {
        // ds_write current phase's tiles (regs already loaded)
        #pragma unroll
        for (int it = 0; it < 8; ++it) {
            int row = 16 * it + (tid >> 4);
            *reinterpret_cast<u16x8*>(&sS[row * 136 + (tid & 15) * 8]) = sreg[it];
        }
        {
            u16x8* ldst = reinterpret_cast<u16x8*>(sW2);
            #pragma unroll
            for (int it = 0; it < 8; ++it)
                ldst[tid + 256 * it] = wreg[it];
        }
        // issue next phase's loads; they drain under this phase's MFMA
        if (t < 4) {
            #pragma unroll
            for (int it = 0; it < 8; ++it) {
                int row = 16 * it + (tid >> 4);
                int node = min(nb + row, N_NODES - 1);
                const unsigned short* src = (t + 1 < 4)
                    ? S + ((size_t)node * 4 + (t + 1)) * 128
                    : xb + (size_t)node * 128;
                sreg[it] = *reinterpret_cast<const u16x8*>(src + (tid & 15) * 8);
            }
            const unsigned short* srcW = (t + 1 < 4) ? w2T + (size_t)(t + 1) * 16384
                                                     : wcatT + (size_t)8 * 16384;
            const u16x8* gsrc = reinterpret_cast<const u16x8*>(srcW);
            #pragma unroll
            for (int it = 0; it < 8; ++it)
                wreg[it] = gsrc[it * 256 + tid];
        }
        __syncthreads();
        #pragma unroll
        for (int ks = 0; ks < 4; ++ks) {
            bf16x8 af[4], bfr[4];
            #pragma unroll
            for (int ft = 0; ft < 4; ++ft)
                af[ft] = *reinterpret_cast<const bf16x8*>(&sW2[ks * 4096 + (64 * wf + 16 * ft + c) * 32 + 8 * g]);
            #pragma unroll
            for (int et = 0; et < 4; ++et)
                bfr[et] = *reinterpret_cast<const bf16x8*>(&sS[(64 * we + 16 * et + c) * 136 + ks * 32 + 8 * g]);
            #pragma unroll
            for (int ft = 0; ft < 4; ++ft)
                #pragma unroll
                for (int et = 0; et < 4; ++et)
                    acc[ft][et] = __builtin_amdgcn_mfma_f32_16x16x32_bf16(af[ft], bfr[et], acc[ft][et], 0, 0, 0);
        }
        __syncthreads();   // MFMA reads done before next phase's ds_write (and before rows[] alias)
    }

    #pragma unroll
    for (int et = 0; et < 4; ++et) {
        int n = 64 * we + 16 * et + c;
        int node = nb + n;
        if (node >= N_NODES) continue;
        const int4 pv4 = *reinterpret_cast<const int4*>(ptr + node * 4);
        const int pe = ptr[node * 4 + 4];
        float cnt4[N_TYPES] = {(float)(pv4.y - pv4.x), (float)(pv4.z - pv4.y),
                               (float)(pv4.w - pv4.z), (float)(pe - pv4.w)};
        #pragma unroll
        for (int ft = 0; ft < 4; ++ft) {
            int f0 = 64 * wf + 16 * ft + 4 * g;
            const float4 sbv = *reinterpret_cast<const float4*>(sb + f0);
            float v[4];
            v[0] = acc[ft][et][0] + sbv.x;
            v[1] = acc[ft][et][1] + sbv.y;
            v[2] = acc[ft][et][2] + sbv.z;
            v[3] = acc[ft][et][3] + sbv.w;
            #pragma unroll
            for (int r = 0; r < 4; ++r) {
                float bs = 0.f;
                #pragma unroll
                for (int t = 0; t < N_TYPES; ++t)
                    bs = fmaf(cnt4[t], sB2[t * 128 + f0 + r], bs);
                v[r] += bs;
            }
            *reinterpret_cast<float4*>(&rows[n * 132 + f0]) = *reinterpret_cast<float4*>(v);
        }
    }
    __syncthreads();

    for (int rr = 0; rr < 32; ++rr) {
        int r = w * 32 + rr;
        int node = nb + r;
        if (node >= N_NODES) break;
        float2 v = *reinterpret_cast<float2*>(&rows[r * 132 + lane * 2]);
        v.x = fmaxf(v.x, 0.f);
        v.y = fmaxf(v.y, 0.f);
        float s = v.x + v.y;
        float ss = v.x * v.x + v.y * v.y;
        #pragma unroll
        for (int m = 1; m < 64; m <<= 1) {
            s  += __shfl_xor(s, m, 64);
            ss += __shfl_xor(ss, m, 64);
        }
        float mu = s * (1.f / 128.f);
        float var = ss * (1.f / 128.f) - mu * mu;
        float rs = rsqrtf(var + LN_EPS);
        const float2 gm = *reinterpret_cast<const float2*>(gamma + lane * 2);
        const float2 bt = *reinterpret_cast<const float2*>(beta + lane * 2);
        float2 o;
        o.x = (v.x - mu) * rs * gm.x + bt.x;
        o.y = (v.y - mu) * rs * gm.y + bt.y;
        *reinterpret_cast<float2*>(out + (size_t)node * D_OUT + lane * 2) = o;
    }
}

extern "C" void kernel_launch(void* const* d_in, const int* in_sizes, int n_in,
                              void* d_out, int out_size, void* d_ws, size_t ws_size,
                              hipStream_t stream) {
    const float* x     = (const float*)d_in[0];
    const int*   ei    = (const int*)d_in[1];
    const int*   attr  = (const int*)d_in[2];
    const float* w1    = (const float*)d_in[3];
    const float* b1    = (const float*)d_in[4];
    const float* w2    = (const float*)d_in[5];
    const float* b2    = (const float*)d_in[6];
    const float* sw    = (const float*)d_in[7];
    const float* sb    = (const float*)d_in[8];
    const float* gamma = (const float*)d_in[9];
    const float* beta  = (const float*)d_in[10];
    float* out = (float*)d_out;

    if (ws_size < WS_TOTAL) return;   // fail visibly rather than corrupt

    char* ws = (char*)d_ws;
    int* ptr    = (int*)(ws + OFF_PTR);
    int* binCur = (int*)(ws + OFF_BCUR);
    unsigned int* binBuf = (unsigned int*)(ws + OFF_BINBUF);
    int* srows  = (int*)(ws + OFF_SROWS);
    unsigned short* xb    = (unsigned short*)(ws + OFF_XB);
    unsigned short* wcatT = (unsigned short*)(ws + OFF_WCAT);
    float*          bias  = (float*)(ws + OFF_BIAS);
    unsigned short* w2T   = (unsigned short*)(ws + OFF_W2T);
    unsigned short* xab   = (unsigned short*)(ws + OFF_XAB);
    unsigned short* S     = (unsigned short*)(ws + OFF_S);

    hipMemsetAsync(binCur, 0, (size_t)NBIN * 4, stream);

    k_prep_all<<<NB_CVT + NB_PREP, 256, 0, stream>>>(
        x, w1, sw, b1, sb, w2, xb, wcatT, bias, w2T);

    k_binA<<<NBA, 256, 0, stream>>>(ei, attr, binCur, binBuf);
    k_binB<<<NBIN, 256, 0, stream>>>(binBuf, binCur, ptr, srows);

    k_gemm1<<<(N_NODES + 127) / 128, 256, 0, stream>>>(xb, wcatT, bias, xab);
    k_agg<<<(N_NODES * 64 + 255) / 256, 256, 0, stream>>>(xab, ptr, srows, S);
    k_gemm2_ln<<<(N_NODES + 127) / 128, 256, 0, stream>>>(
        S, w2T, wcatT, xb, b2, sb, ptr, gamma, beta, out);
}

// Round 15
// 167.461 us; speedup vs baseline: 1.0080x; 1.0080x over previous
//
#include <hip/hip_runtime.h>

#define N_NODES 50000
#define N_EDGES 800000
#define D_IN 128
#define D_OUT 128
#define N_TYPES 4
#define LN_EPS 1e-5f
#define N_BUCKETS (N_TYPES * N_NODES)   // 200000, keyed as node*4+type
#define NJT 9                            // 8 w1 halves + 1 self (self slab feeds gemm2)

// binned (col,type) sort
#define NBIN 196                          // col >> 8  (256 nodes per bin)
#define BIN_CAP 8192                      // mean 4096/bin, ~64 sigma headroom
#define TILE_A 2048
#define NBA ((N_EDGES + TILE_A - 1) / TILE_A)   // 391

typedef __attribute__((ext_vector_type(4))) float f32x4;
typedef __attribute__((ext_vector_type(8))) __bf16 bf16x8;
typedef __attribute__((ext_vector_type(8))) unsigned short u16x8;

// ---- workspace layout (bytes), 256-aligned sections ----
constexpr size_t wsal(size_t x) { return (x + 255) & ~size_t(255); }
constexpr size_t OFF_PTR    = 0;                                              // (200001)*4
constexpr size_t OFF_BCUR   = OFF_PTR   + wsal((size_t)(N_BUCKETS + 1) * 4);  // 256*4
constexpr size_t OFF_BINBUF = OFF_BCUR  + wsal((size_t)256 * 4);              // 196*8192*4 = 6.4MB
constexpr size_t OFF_SROWS  = OFF_BINBUF + wsal((size_t)NBIN * BIN_CAP * 4);  // 800000*4
constexpr size_t OFF_XB     = OFF_SROWS + wsal((size_t)N_EDGES * 4);          // 12.8MB
constexpr size_t OFF_WCAT   = OFF_XB    + wsal((size_t)N_NODES * D_IN * 2);
constexpr size_t OFF_BIAS   = OFF_WCAT  + wsal((size_t)NJT * 4 * 128 * 32 * 2);
constexpr size_t OFF_W2T    = OFF_BIAS  + wsal((size_t)NJT * 128 * 4);
constexpr size_t OFF_XAB    = OFF_W2T   + wsal((size_t)N_TYPES * 4 * 128 * 32 * 2);
constexpr size_t OFF_S      = OFF_XAB   + wsal((size_t)8 * N_NODES * 128 * 2);   // 102.4MB
constexpr size_t WS_TOTAL   = OFF_S     + wsal((size_t)N_BUCKETS * 128 * 2);     // +51.2MB ≈ 178MB

__device__ __forceinline__ unsigned short f2bf(float f) {
    unsigned int u = __builtin_bit_cast(unsigned int, f);
    u += 0x7FFFu + ((u >> 16) & 1u);   // RNE; inputs finite
    return (unsigned short)(u >> 16);
}
__device__ __forceinline__ float bf2f_lo(unsigned int u) { return __builtin_bit_cast(float, u << 16); }
__device__ __forceinline__ float bf2f_hi(unsigned int u) { return __builtin_bit_cast(float, u & 0xFFFF0000u); }

// ---------------- merged prep: x->bf16 | weight transposes ----------------
#define PREP_N0 (NJT * 4 * 128 * 32)
#define PREP_N1 (NJT * 128)
#define PREP_N2 (N_TYPES * 4 * 128 * 32)
#define NB_CVT  (N_NODES * D_IN / 4 / 256)                       // 6250 (exact)
#define NB_PREP ((PREP_N0 + PREP_N1 + PREP_N2 + 255) / 256)      // 837

__global__ __launch_bounds__(256) void k_prep_all(
    const float* __restrict__ x,
    const float* __restrict__ w1, const float* __restrict__ sw,
    const float* __restrict__ b1, const float* __restrict__ sb,
    const float* __restrict__ w2,
    unsigned short* __restrict__ xb,
    unsigned short* __restrict__ wcatT, float* __restrict__ bias,
    unsigned short* __restrict__ w2T)
{
    const int bx = blockIdx.x;
    const int tid = threadIdx.x;
    if (bx < NB_CVT) {
        int i = bx * 256 + tid;
        const float4 v = reinterpret_cast<const float4*>(x)[i];
        ushort4 o;
        o.x = f2bf(v.x); o.y = f2bf(v.y); o.z = f2bf(v.z); o.w = f2bf(v.w);
        reinterpret_cast<ushort4*>(xb)[i] = o;
        return;
    }
    int gid = (bx - NB_CVT) * 256 + tid;
    if (gid < PREP_N0) {
        // wcatT[jt][ks][jm][kk] = Wcat[ks*32+kk][jt*128+jm]
        int kk = gid & 31;
        int jm = (gid >> 5) & 127;
        int ks = (gid >> 12) & 3;
        int jt = gid >> 14;
        int k  = ks * 32 + kk;
        float v;
        if (jt < 8) {
            int t = jt >> 1, half = jt & 1;
            v = w1[((size_t)t * 256 + half * 128 + k) * 128 + jm];
        } else {
            v = sw[(size_t)k * 128 + jm];
        }
        wcatT[gid] = f2bf(v);
        return;
    }
    gid -= PREP_N0;
    if (gid < PREP_N1) {
        int jt = gid >> 7, jm = gid & 127;
        float v = 0.f;
        if (jt < 8) { if (jt & 1) v = b1[(jt >> 1) * 128 + jm]; }
        else v = sb[jm];
        bias[gid] = v;
        return;
    }
    gid -= PREP_N1;
    if (gid < PREP_N2) {
        // w2T[t][ks][f][kk] = w2[t][ks*32+kk][f]
        int kk = gid & 31;
        int f  = (gid >> 5) & 127;
        int ks = (gid >> 12) & 3;
        int t  = gid >> 14;
        float v = w2[((size_t)t * 128 + ks * 32 + kk) * 128 + f];
        w2T[gid] = f2bf(v);
    }
}

// ---------------- binned (col,type) sort, pass A ----------------
// record = c_local[8] << 21 | t[2] << 19 | absrow[19], absrow = 2t*N + srcRow < 350000 < 2^19
__global__ __launch_bounds__(256) void k_binA(
    const int* __restrict__ ei, const int* __restrict__ attr,
    int* __restrict__ binCur, unsigned int* __restrict__ binBuf)
{
    __shared__ int hist[NBIN];
    __shared__ int base[NBIN];
    const int tid = threadIdx.x;
    const int e0 = blockIdx.x * TILE_A;
    if (tid < NBIN) hist[tid] = 0;
    __syncthreads();
    #pragma unroll
    for (int it = 0; it < TILE_A / 256; ++it) {
        int e = e0 + it * 256 + tid;
        if (e < N_EDGES) atomicAdd(&hist[ei[N_EDGES + e] >> 8], 1);
    }
    __syncthreads();
    if (tid < NBIN) {
        base[tid] = atomicAdd(&binCur[tid], hist[tid]);
        hist[tid] = 0;   // reuse as local rank counter
    }
    __syncthreads();
    #pragma unroll
    for (int it = 0; it < TILE_A / 256; ++it) {
        int e = e0 + it * 256 + tid;
        if (e < N_EDGES) {
            int c = ei[N_EDGES + e];
            int t = attr[e];
            int row = ei[e];
            int bin = c >> 8;
            int lr = atomicAdd(&hist[bin], 1);
            int dst = base[bin] + lr;
            unsigned int rec = ((unsigned int)(c & 255) << 21) | ((unsigned int)t << 19)
                             | (unsigned int)(2 * t * N_NODES + row);
            if (dst < BIN_CAP) binBuf[(size_t)bin * BIN_CAP + dst] = rec;
        }
    }
}

// ---------------- pass B: per-bin LDS counting sort -> ptr + srows (all coalesced) ----------------
__global__ __launch_bounds__(256) void k_binB(
    const unsigned int* __restrict__ binBuf, const int* __restrict__ binCur,
    int* __restrict__ ptr, int* __restrict__ srows)
{
    __shared__ unsigned int recs[BIN_CAP];   // 32KB
    __shared__ int stage[BIN_CAP];           // 32KB
    __shared__ int boff[1024];               // bucket excl offsets, then cursors (4KB)
    __shared__ int sred[256];
    const int b = blockIdx.x, tid = threadIdx.x;
    const int cntb = min(binCur[b], BIN_CAP);

    for (int i = tid; i < cntb; i += 256)
        recs[i] = binBuf[(size_t)b * BIN_CAP + i];

    // binBase = sum of binCur over bins < b (redundant tree-reduce per block)
    int myv = (tid < NBIN && tid < b) ? binCur[tid] : 0;
    sred[tid] = myv;
    __syncthreads();
    #pragma unroll
    for (int d = 128; d > 0; d >>= 1) {
        if (tid < d) sred[tid] += sred[tid + d];
        __syncthreads();
    }
    const int binBase = sred[0];
    __syncthreads();

    // bucket histogram (key = clocal*4 + t, matches global bucket order)
    for (int k = tid; k < 1024; k += 256) boff[k] = 0;
    __syncthreads();
    for (int i = tid; i < cntb; i += 256)
        atomicAdd(&boff[(recs[i] >> 19) & 1023], 1);
    __syncthreads();

    // exclusive scan of the 1024 counts (each thread owns 4)
    const int c0 = boff[tid * 4], c1 = boff[tid * 4 + 1], c2 = boff[tid * 4 + 2], c3 = boff[tid * 4 + 3];
    const int ts = c0 + c1 + c2 + c3;
    sred[tid] = ts;
    __syncthreads();
    #pragma unroll
    for (int d = 1; d < 256; d <<= 1) {
        int add = (tid >= d) ? sred[tid - d] : 0;
        __syncthreads();
        sred[tid] += add;
        __syncthreads();
    }
    const int run = sred[tid] - ts;
    const int o0 = run, o1 = run + c0, o2 = run + c0 + c1, o3 = run + c0 + c1 + c2;
    boff[tid * 4 + 0] = o0; boff[tid * 4 + 1] = o1;
    boff[tid * 4 + 2] = o2; boff[tid * 4 + 3] = o3;
    // ptr for this bin's buckets (contiguous 4KB)
    const int gb = b * 1024 + tid * 4;
    if (gb + 3 < N_BUCKETS) {
        int4 pv; pv.x = binBase + o0; pv.y = binBase + o1; pv.z = binBase + o2; pv.w = binBase + o3;
        *reinterpret_cast<int4*>(ptr + gb) = pv;
    } else {
        if (gb + 0 < N_BUCKETS) ptr[gb + 0] = binBase + o0;
        if (gb + 1 < N_BUCKETS) ptr[gb + 1] = binBase + o1;
        if (gb + 2 < N_BUCKETS) ptr[gb + 2] = binBase + o2;
        if (gb + 3 < N_BUCKETS) ptr[gb + 3] = binBase + o3;
    }
    if (b == 0 && tid == 0) ptr[N_BUCKETS] = N_EDGES;
    __syncthreads();

    // scatter into LDS stage (boff now acts as cursor)
    for (int i = tid; i < cntb; i += 256) {
        unsigned int r = recs[i];
        int pos = atomicAdd(&boff[(r >> 19) & 1023], 1);
        stage[pos] = (int)(r & 0x7FFFFu);
    }
    __syncthreads();
    // stream out fully coalesced
    for (int i = tid; i < cntb; i += 256)
        srows[binBase + i] = stage[i];
}

// ---------------- GEMM1: x staged once per block; 4 jt slabs per block (grid.y=2) ----------------
// Per phase: ds_write slab (regs) -> barrier -> ISSUE next slab loads -> MFMA + epilogue -> barrier.
// The phase-end barrier's vmcnt(0) drain lands exactly where the next ds_write needs the data,
// so load latency hides under MFMA+epilogue instead of serializing phases.
__global__ __launch_bounds__(256, 2) void k_gemm1(
    const unsigned short* __restrict__ xb,
    const unsigned short* __restrict__ wcatT,
    const float* __restrict__ bias,
    unsigned short* __restrict__ xab)
{
    const int nb = blockIdx.x * 128;
    const int jt0 = blockIdx.y * 4;

    __shared__ __align__(16) unsigned short sX[128 * 136];  // x rows [n][k], staged once
    __shared__ __align__(16) unsigned short sW[128 * 136];  // weight slab [f][ks*32+kk]

    const int tid = threadIdx.x;
    const int lane = tid & 63;
    const int w = tid >> 6;
    const int g = lane >> 4;
    const int c = lane & 15;
    const int wf = w >> 1;   // j half
    const int we = w & 1;    // n half

    #pragma unroll
    for (int it = 0; it < 8; ++it) {
        int row = 16 * it + (tid >> 4);
        int node = min(nb + row, N_NODES - 1);
        const u16x8 v = *reinterpret_cast<const u16x8*>(xb + (size_t)node * D_IN + (tid & 15) * 8);
        *reinterpret_cast<u16x8*>(&sX[row * 136 + (tid & 15) * 8]) = v;
    }

    // prologue: first slab into registers
    u16x8 wreg[8];
    {
        const u16x8* gsrc = reinterpret_cast<const u16x8*>(wcatT + (size_t)jt0 * 16384);
        #pragma unroll
        for (int i = 0; i < 8; ++i) wreg[i] = gsrc[i * 256 + tid];
    }

    for (int j = 0; j < 4; ++j) {
        const int jt = jt0 + j;
        // ds_write slab jt: global [ks][f][kk] order -> LDS [f][136]
        #pragma unroll
        for (int i = 0; i < 8; ++i) {
            int idx = i * 256 + tid;
            int ks = idx >> 9, f = (idx >> 2) & 127, k8 = idx & 3;
            *reinterpret_cast<u16x8*>(&sW[f * 136 + ks * 32 + k8 * 8]) = wreg[i];
        }
        __syncthreads();   // sW (and sX on j=0) visible

        // NOW issue next slab's loads; drain happens at the phase-end barrier
        if (j < 3) {
            const u16x8* gsrc = reinterpret_cast<const u16x8*>(wcatT + (size_t)(jt + 1) * 16384);
            #pragma unroll
            for (int i = 0; i < 8; ++i) wreg[i] = gsrc[i * 256 + tid];
        }

        f32x4 acc[4][4];
        #pragma unroll
        for (int ft = 0; ft < 4; ++ft)
            #pragma unroll
            for (int et = 0; et < 4; ++et)
                acc[ft][et] = f32x4{0.f, 0.f, 0.f, 0.f};

        #pragma unroll
        for (int ks = 0; ks < 4; ++ks) {
            bf16x8 af[4], bfr[4];
            #pragma unroll
            for (int ft = 0; ft < 4; ++ft)
                af[ft] = *reinterpret_cast<const bf16x8*>(&sW[(64 * wf + 16 * ft + c) * 136 + ks * 32 + 8 * g]);
            #pragma unroll
            for (int et = 0; et < 4; ++et)
                bfr[et] = *reinterpret_cast<const bf16x8*>(&sX[(64 * we + 16 * et + c) * 136 + ks * 32 + 8 * g]);
            #pragma unroll
            for (int ft = 0; ft < 4; ++ft)
                #pragma unroll
                for (int et = 0; et < 4; ++et)
                    acc[ft][et] = __builtin_amdgcn_mfma_f32_16x16x32_bf16(af[ft], bfr[et], acc[ft][et], 0, 0, 0);
        }

        // epilogue: +bias, pack, write direct to global (wave-local rows -> lines merge in L2)
        float bv[4][4];
        #pragma unroll
        for (int ft = 0; ft < 4; ++ft)
            #pragma unroll
            for (int r = 0; r < 4; ++r)
                bv[ft][r] = bias[jt * 128 + 64 * wf + 16 * ft + 4 * g + r];
        #pragma unroll
        for (int et = 0; et < 4; ++et) {
            int n = 64 * we + 16 * et + c;
            int node = nb + n;
            if (node < N_NODES) {
                unsigned int* orow = reinterpret_cast<unsigned int*>(
                    xab + ((size_t)jt * N_NODES + node) * 128);
                #pragma unroll
                for (int ft = 0; ft < 4; ++ft) {
                    int f0 = 64 * wf + 16 * ft + 4 * g;
                    uint2 pk;
                    pk.x = (unsigned int)f2bf(acc[ft][et][0] + bv[ft][0])
                         | ((unsigned int)f2bf(acc[ft][et][1] + bv[ft][1]) << 16);
                    pk.y = (unsigned int)f2bf(acc[ft][et][2] + bv[ft][2])
                         | ((unsigned int)f2bf(acc[ft][et][3] + bv[ft][3]) << 16);
                    *reinterpret_cast<uint2*>(orow + (f0 >> 1)) = pk;
                }
            }
        }
        __syncthreads();   // drains next-slab loads; MFMA reads of sW done before next ds_write
    }
}

// ---------------- node-major aggregation: one wave per node, scalar control plane ----------------
// One coalesced chunk load of <=64 edge rows per node, then per-edge v_readlane (no per-edge VMEM).
__global__ __launch_bounds__(256) void k_agg(const unsigned short* __restrict__ xab,
                                             const int* __restrict__ ptr,
                                             const int* __restrict__ srows,
                                             unsigned short* __restrict__ S)
{
    const int n = (blockIdx.x * 256 + threadIdx.x) >> 6;   // node = global wave id
    if (n >= N_NODES) return;
    const int lane = threadIdx.x & 63;
    const unsigned int* x32 = reinterpret_cast<const unsigned int*>(xab);

    int seg[5];
    #pragma unroll
    for (int t = 0; t < 5; ++t)
        seg[t] = __builtin_amdgcn_readfirstlane(ptr[4 * n + t]);

    float xbl[4], xbh[4];
    #pragma unroll
    for (int t = 0; t < 4; ++t) {
        unsigned int v = x32[((size_t)(2 * t + 1) * N_NODES + n) * 64 + lane];
        xbl[t] = bf2f_lo(v); xbh[t] = bf2f_hi(v);
    }

    float al[4] = {0.f, 0.f, 0.f, 0.f}, ah[4] = {0.f, 0.f, 0.f, 0.f};

    const int p0 = seg[0], pE = seg[4];
    for (int co = p0; co < pE; co += 64) {
        const int rem = pE - co;
        const int cv = srows[co + min(lane, rem - 1)];   // one coalesced load covers the chunk
        const int ce = min(co + 64, pE);
        #pragma unroll
        for (int t = 0; t < 4; ++t) {
            const int lo = max(seg[t], co);
            const int hi = min(seg[t + 1], ce);
            int j = lo;
            for (; j + 4 <= hi; j += 4) {
                int a0 = __builtin_amdgcn_readlane(cv, j - co);
                int a1 = __builtin_amdgcn_readlane(cv, j + 1 - co);
                int a2 = __builtin_amdgcn_readlane(cv, j + 2 - co);
                int a3 = __builtin_amdgcn_readlane(cv, j + 3 - co);
                unsigned int v0 = x32[(size_t)a0 * 64 + lane];
                unsigned int v1 = x32[(size_t)a1 * 64 + lane];
                unsigned int v2 = x32[(size_t)a2 * 64 + lane];
                unsigned int v3 = x32[(size_t)a3 * 64 + lane];
                al[t] += fmaxf(bf2f_lo(v0) + xbl[t], 0.f) + fmaxf(bf2f_lo(v1) + xbl[t], 0.f)
                       + fmaxf(bf2f_lo(v2) + xbl[t], 0.f) + fmaxf(bf2f_lo(v3) + xbl[t], 0.f);
                ah[t] += fmaxf(bf2f_hi(v0) + xbh[t], 0.f) + fmaxf(bf2f_hi(v1) + xbh[t], 0.f)
                       + fmaxf(bf2f_hi(v2) + xbh[t], 0.f) + fmaxf(bf2f_hi(v3) + xbh[t], 0.f);
            }
            for (; j < hi; ++j) {
                int a = __builtin_amdgcn_readlane(cv, j - co);
                unsigned int v = x32[(size_t)a * 64 + lane];
                al[t] += fmaxf(bf2f_lo(v) + xbl[t], 0.f);
                ah[t] += fmaxf(bf2f_hi(v) + xbh[t], 0.f);
            }
        }
    }

    unsigned int* S32 = reinterpret_cast<unsigned int*>(S);
    #pragma unroll
    for (int t = 0; t < 4; ++t)
        S32[((size_t)n * 4 + t) * 64 + lane] =
            (unsigned int)f2bf(al[t]) | ((unsigned int)f2bf(ah[t]) << 16);
}

// ---------------- GEMM2 (+self-proj) + ReLU + LayerNorm fused, issue-after-barrier staging ----------------
__global__ __launch_bounds__(256, 2) void k_gemm2_ln(
    const unsigned short* __restrict__ S,      // node-major [n][4][128]
    const unsigned short* __restrict__ w2T,
    const unsigned short* __restrict__ wcatT,   // slab 8 = self weights
    const unsigned short* __restrict__ xb,
    const float* __restrict__ b2,
    const float* __restrict__ sb,
    const int* __restrict__ ptr,                // counts via diffs
    const float* __restrict__ gamma,
    const float* __restrict__ beta,
    float* __restrict__ out)
{
    const int nb = blockIdx.x * 128;
    __shared__ __align__(16) unsigned char sm[128 * 136 * 2 + 4 * 128 * 32 * 2 + 512 * 4];
    unsigned short* sS  = reinterpret_cast<unsigned short*>(sm);               // [128*136]
    unsigned short* sW2 = reinterpret_cast<unsigned short*>(sm + 34816);       // [4*128*32]
    float* sB2          = reinterpret_cast<float*>(sm + 34816 + 32768);        // [512]
    float* rows         = reinterpret_cast<float*>(sm);                        // [128][132] alias, post-MFMA

    const int tid = threadIdx.x;
    const int lane = tid & 63;
    const int w = tid >> 6;
    const int g = lane >> 4;
    const int c = lane & 15;
    const int wf = w >> 1;   // f half
    const int we = w & 1;    // n half

    sB2[tid] = b2[tid];
    sB2[tid + 256] = b2[tid + 256];

    f32x4 acc[4][4];
    #pragma unroll
    for (int ft = 0; ft < 4; ++ft)
        #pragma unroll
        for (int et = 0; et < 4; ++et)
            acc[ft][et] = f32x4{0.f, 0.f, 0.f, 0.f};

    // prologue: phase-0 sources into registers
    u16x8 sreg[8], wreg[8];
    {
        #pragma unroll
        for (int it = 0; it < 8; ++it) {
            int row = 16 * it + (tid >> 4);
            int node = min(nb + row, N_NODES - 1);
            sreg[it] = *reinterpret_cast<const u16x8*>(S + ((size_t)node * 4 + 0) * 128 + (tid & 15) * 8);
        }
        const u16x8* gsrc = reinterpret_cast<const u16x8*>(w2T);
        #pragma unroll
        for (int it = 0; it < 8; ++it)
            wreg[it] = gsrc[it * 256 + tid];
    }

    for (int t = 0; t < 5; ++t) {
        // ds_write current phase's tiles (regs already loaded)
        #pragma unroll
        for (int it = 0; it < 8; ++it) {
            int row = 16 * it + (tid >> 4);
            *reinterpret_cast<u16x8*>(&sS[row * 136 + (tid & 15) * 8]) = sreg[it];
        }
        {
            u16x8* ldst = reinterpret_cast<u16x8*>(sW2);
            #pragma unroll
            for (int it = 0; it < 8; ++it)
                ldst[tid + 256 * it] = wreg[it];
        }
        __syncthreads();   // tiles visible

        // NOW issue next phase's loads; they drain at the phase-end barrier (under MFMA)
        if (t < 4) {
            #pragma unroll
            for (int it = 0; it < 8; ++it) {
                int row = 16 * it + (tid >> 4);
                int node = min(nb + row, N_NODES - 1);
                const unsigned short* src = (t + 1 < 4)
                    ? S + ((size_t)node * 4 + (t + 1)) * 128
                    : xb + (size_t)node * 128;
                sreg[it] = *reinterpret_cast<const u16x8*>(src + (tid & 15) * 8);
            }
            const unsigned short* srcW = (t + 1 < 4) ? w2T + (size_t)(t + 1) * 16384
                                                     : wcatT + (size_t)8 * 16384;
            const u16x8* gsrc = reinterpret_cast<const u16x8*>(srcW);
            #pragma unroll
            for (int it = 0; it < 8; ++it)
                wreg[it] = gsrc[it * 256 + tid];
        }
        #pragma unroll
        for (int ks = 0; ks < 4; ++ks) {
            bf16x8 af[4], bfr[4];
            #pragma unroll
            for (int ft = 0; ft < 4; ++ft)
                af[ft] = *reinterpret_cast<const bf16x8*>(&sW2[ks * 4096 + (64 * wf + 16 * ft + c) * 32 + 8 * g]);
            #pragma unroll
            for (int et = 0; et < 4; ++et)
                bfr[et] = *reinterpret_cast<const bf16x8*>(&sS[(64 * we + 16 * et + c) * 136 + ks * 32 + 8 * g]);
            #pragma unroll
            for (int ft = 0; ft < 4; ++ft)
                #pragma unroll
                for (int et = 0; et < 4; ++et)
                    acc[ft][et] = __builtin_amdgcn_mfma_f32_16x16x32_bf16(af[ft], bfr[et], acc[ft][et], 0, 0, 0);
        }
        __syncthreads();   // drains next-phase loads; MFMA reads done before next ds_write / rows[] alias
    }

    #pragma unroll
    for (int et = 0; et < 4; ++et) {
        int n = 64 * we + 16 * et + c;
        int node = nb + n;
        if (node >= N_NODES) continue;
        const int4 pv4 = *reinterpret_cast<const int4*>(ptr + node * 4);
        const int pe = ptr[node * 4 + 4];
        float cnt4[N_TYPES] = {(float)(pv4.y - pv4.x), (float)(pv4.z - pv4.y),
                               (float)(pv4.w - pv4.z), (float)(pe - pv4.w)};
        #pragma unroll
        for (int ft = 0; ft < 4; ++ft) {
            int f0 = 64 * wf + 16 * ft + 4 * g;
            const float4 sbv = *reinterpret_cast<const float4*>(sb + f0);
            float v[4];
            v[0] = acc[ft][et][0] + sbv.x;
            v[1] = acc[ft][et][1] + sbv.y;
            v[2] = acc[ft][et][2] + sbv.z;
            v[3] = acc[ft][et][3] + sbv.w;
            #pragma unroll
            for (int r = 0; r < 4; ++r) {
                float bs = 0.f;
                #pragma unroll
                for (int t = 0; t < N_TYPES; ++t)
                    bs = fmaf(cnt4[t], sB2[t * 128 + f0 + r], bs);
                v[r] += bs;
            }
            *reinterpret_cast<float4*>(&rows[n * 132 + f0]) = *reinterpret_cast<float4*>(v);
        }
    }
    __syncthreads();

    for (int rr = 0; rr < 32; ++rr) {
        int r = w * 32 + rr;
        int node = nb + r;
        if (node >= N_NODES) break;
        float2 v = *reinterpret_cast<float2*>(&rows[r * 132 + lane * 2]);
        v.x = fmaxf(v.x, 0.f);
        v.y = fmaxf(v.y, 0.f);
        float s = v.x + v.y;
        float ss = v.x * v.x + v.y * v.y;
        #pragma unroll
        for (int m = 1; m < 64; m <<= 1) {
            s  += __shfl_xor(s, m, 64);
            ss += __shfl_xor(ss, m, 64);
        }
        float mu = s * (1.f / 128.f);
        float var = ss * (1.f / 128.f) - mu * mu;
        float rs = rsqrtf(var + LN_EPS);
        const float2 gm = *reinterpret_cast<const float2*>(gamma + lane * 2);
        const float2 bt = *reinterpret_cast<const float2*>(beta + lane * 2);
        float2 o;
        o.x = (v.x - mu) * rs * gm.x + bt.x;
        o.y = (v.y - mu) * rs * gm.y + bt.y;
        *reinterpret_cast<float2*>(out + (size_t)node * D_OUT + lane * 2) = o;
    }
}

extern "C" void kernel_launch(void* const* d_in, const int* in_sizes, int n_in,
                              void* d_out, int out_size, void* d_ws, size_t ws_size,
                              hipStream_t stream) {
    const float* x     = (const float*)d_in[0];
    const int*   ei    = (const int*)d_in[1];
    const int*   attr  = (const int*)d_in[2];
    const float* w1    = (const float*)d_in[3];
    const float* b1    = (const float*)d_in[4];
    const float* w2    = (const float*)d_in[5];
    const float* b2    = (const float*)d_in[6];
    const float* sw    = (const float*)d_in[7];
    const float* sb    = (const float*)d_in[8];
    const float* gamma = (const float*)d_in[9];
    const float* beta  = (const float*)d_in[10];
    float* out = (float*)d_out;

    if (ws_size < WS_TOTAL) return;   // fail visibly rather than corrupt

    char* ws = (char*)d_ws;
    int* ptr    = (int*)(ws + OFF_PTR);
    int* binCur = (int*)(ws + OFF_BCUR);
    unsigned int* binBuf = (unsigned int*)(ws + OFF_BINBUF);
    int* srows  = (int*)(ws + OFF_SROWS);
    unsigned short* xb    = (unsigned short*)(ws + OFF_XB);
    unsigned short* wcatT = (unsigned short*)(ws + OFF_WCAT);
    float*          bias  = (float*)(ws + OFF_BIAS);
    unsigned short* w2T   = (unsigned short*)(ws + OFF_W2T);
    unsigned short* xab   = (unsigned short*)(ws + OFF_XAB);
    unsigned short* S     = (unsigned short*)(ws + OFF_S);

    hipMemsetAsync(binCur, 0, (size_t)NBIN * 4, stream);

    k_prep_all<<<NB_CVT + NB_PREP, 256, 0, stream>>>(
        x, w1, sw, b1, sb, w2, xb, wcatT, bias, w2T);

    k_binA<<<NBA, 256, 0, stream>>>(ei, attr, binCur, binBuf);
    k_binB<<<NBIN, 256, 0, stream>>>(binBuf, binCur, ptr, srows);

    k_gemm1<<<dim3((N_NODES + 127) / 128, 2), 256, 0, stream>>>(xb, wcatT, bias, xab);
    k_agg<<<(N_NODES * 64 + 255) / 256, 256, 0, stream>>>(xab, ptr, srows, S);
    k_gemm2_ln<<<(N_NODES + 127) / 128, 256, 0, stream>>>(
        S, w2T, wcatT, xb, b2, sb, ptr, gamma, beta, out);
}

// Round 16
// 144.870 us; speedup vs baseline: 1.1652x; 1.1559x over previous
//
#include <hip/hip_runtime.h>

#define N_NODES 50000
#define N_EDGES 800000
#define D_IN 128
#define D_OUT 128
#define N_TYPES 4
#define LN_EPS 1e-5f
#define N_BUCKETS (N_TYPES * N_NODES)   // 200000, keyed as node*4+type
#define NJT 9                            // 8 w1 halves + 1 self (self slab feeds gemm2)

// binned (col,type) sort
#define NBIN 196                          // col >> 8  (256 nodes per bin)
#define BIN_CAP 8192                      // mean 4096/bin, ~64 sigma headroom
#define TILE_A 2048
#define NBA ((N_EDGES + TILE_A - 1) / TILE_A)   // 391

// gemm1 grid decomposition (one jt slab per block, round-11 proven form)
#define G1_NX ((N_NODES + 127) / 128)     // 391

typedef __attribute__((ext_vector_type(4))) float f32x4;
typedef __attribute__((ext_vector_type(8))) __bf16 bf16x8;
typedef __attribute__((ext_vector_type(8))) unsigned short u16x8;

// ---- workspace layout (bytes), 256-aligned sections ----
constexpr size_t wsal(size_t x) { return (x + 255) & ~size_t(255); }
constexpr size_t OFF_PTR    = 0;                                              // (200001)*4
constexpr size_t OFF_BCUR   = OFF_PTR   + wsal((size_t)(N_BUCKETS + 1) * 4);  // 256*4
constexpr size_t OFF_BINBUF = OFF_BCUR  + wsal((size_t)256 * 4);              // 196*8192*4 = 6.4MB
constexpr size_t OFF_SROWS  = OFF_BINBUF + wsal((size_t)NBIN * BIN_CAP * 4);  // 800000*4
constexpr size_t OFF_XB     = OFF_SROWS + wsal((size_t)N_EDGES * 4);          // 12.8MB
constexpr size_t OFF_WCAT   = OFF_XB    + wsal((size_t)N_NODES * D_IN * 2);
constexpr size_t OFF_BIAS   = OFF_WCAT  + wsal((size_t)NJT * 4 * 128 * 32 * 2);
constexpr size_t OFF_W2T    = OFF_BIAS  + wsal((size_t)NJT * 128 * 4);
constexpr size_t OFF_XAB    = OFF_W2T   + wsal((size_t)N_TYPES * 4 * 128 * 32 * 2);
constexpr size_t OFF_S      = OFF_XAB   + wsal((size_t)8 * N_NODES * 128 * 2);   // 102.4MB
constexpr size_t WS_TOTAL   = OFF_S     + wsal((size_t)N_BUCKETS * 128 * 2);     // +51.2MB ≈ 178MB

__device__ __forceinline__ unsigned short f2bf(float f) {
    unsigned int u = __builtin_bit_cast(unsigned int, f);
    u += 0x7FFFu + ((u >> 16) & 1u);   // RNE; inputs finite
    return (unsigned short)(u >> 16);
}
__device__ __forceinline__ float bf2f_lo(unsigned int u) { return __builtin_bit_cast(float, u << 16); }
__device__ __forceinline__ float bf2f_hi(unsigned int u) { return __builtin_bit_cast(float, u & 0xFFFF0000u); }

// ---------------- K1: binA | x->bf16 cvt | weight transposes (independent, fused grid) ----------------
#define PREP_N0 (NJT * 4 * 128 * 32)
#define PREP_N1 (NJT * 128)
#define PREP_N2 (N_TYPES * 4 * 128 * 32)
#define NB_CVT  (N_NODES * D_IN / 4 / 256)                       // 6250 (exact)
#define NB_PREP ((PREP_N0 + PREP_N1 + PREP_N2 + 255) / 256)      // 837

__global__ __launch_bounds__(256) void k_prep_binA(
    const float* __restrict__ x,
    const float* __restrict__ w1, const float* __restrict__ sw,
    const float* __restrict__ b1, const float* __restrict__ sb,
    const float* __restrict__ w2,
    const int* __restrict__ ei, const int* __restrict__ attr,
    unsigned short* __restrict__ xb,
    unsigned short* __restrict__ wcatT, float* __restrict__ bias,
    unsigned short* __restrict__ w2T,
    int* __restrict__ binCur, unsigned int* __restrict__ binBuf)
{
    __shared__ int sm[2 * NBIN];   // binA branch only
    const int bx = blockIdx.x;
    const int tid = threadIdx.x;

    if (bx < NBA) {
        // ---- binA: record = c_local[8]<<21 | t[2]<<19 | absrow[19] ----
        int* hist = sm;
        int* base = sm + NBIN;
        const int e0 = bx * TILE_A;
        if (tid < NBIN) hist[tid] = 0;
        __syncthreads();
        #pragma unroll
        for (int it = 0; it < TILE_A / 256; ++it) {
            int e = e0 + it * 256 + tid;
            if (e < N_EDGES) atomicAdd(&hist[ei[N_EDGES + e] >> 8], 1);
        }
        __syncthreads();
        if (tid < NBIN) {
            base[tid] = atomicAdd(&binCur[tid], hist[tid]);
            hist[tid] = 0;   // reuse as local rank counter
        }
        __syncthreads();
        #pragma unroll
        for (int it = 0; it < TILE_A / 256; ++it) {
            int e = e0 + it * 256 + tid;
            if (e < N_EDGES) {
                int c = ei[N_EDGES + e];
                int t = attr[e];
                int row = ei[e];
                int bin = c >> 8;
                int lr = atomicAdd(&hist[bin], 1);
                int dst = base[bin] + lr;
                unsigned int rec = ((unsigned int)(c & 255) << 21) | ((unsigned int)t << 19)
                                 | (unsigned int)(2 * t * N_NODES + row);
                if (dst < BIN_CAP) binBuf[(size_t)bin * BIN_CAP + dst] = rec;
            }
        }
        return;
    }
    const int pb = bx - NBA;
    if (pb < NB_CVT) {
        int i = pb * 256 + tid;
        const float4 v = reinterpret_cast<const float4*>(x)[i];
        ushort4 o;
        o.x = f2bf(v.x); o.y = f2bf(v.y); o.z = f2bf(v.z); o.w = f2bf(v.w);
        reinterpret_cast<ushort4*>(xb)[i] = o;
        return;
    }
    int gid = (pb - NB_CVT) * 256 + tid;
    if (gid < PREP_N0) {
        // wcatT[jt][ks][jm][kk] = Wcat[ks*32+kk][jt*128+jm]
        int kk = gid & 31;
        int jm = (gid >> 5) & 127;
        int ks = (gid >> 12) & 3;
        int jt = gid >> 14;
        int k  = ks * 32 + kk;
        float v;
        if (jt < 8) {
            int t = jt >> 1, half = jt & 1;
            v = w1[((size_t)t * 256 + half * 128 + k) * 128 + jm];
        } else {
            v = sw[(size_t)k * 128 + jm];
        }
        wcatT[gid] = f2bf(v);
        return;
    }
    gid -= PREP_N0;
    if (gid < PREP_N1) {
        int jt = gid >> 7, jm = gid & 127;
        float v = 0.f;
        if (jt < 8) { if (jt & 1) v = b1[(jt >> 1) * 128 + jm]; }
        else v = sb[jm];
        bias[gid] = v;
        return;
    }
    gid -= PREP_N1;
    if (gid < PREP_N2) {
        // w2T[t][ks][f][kk] = w2[t][ks*32+kk][f]
        int kk = gid & 31;
        int f  = (gid >> 5) & 127;
        int ks = (gid >> 12) & 3;
        int t  = gid >> 14;
        float v = w2[((size_t)t * 128 + ks * 32 + kk) * 128 + f];
        w2T[gid] = f2bf(v);
    }
}

// ---------------- K2: binB (196 blocks) | gemm1 (391x8 blocks, round-11 form) fused ----------------
// binB needs only binA (K1); gemm1 needs only prep (K1) -> independent within K2.
__global__ __launch_bounds__(256, 2) void k_binB_gemm1(
    const unsigned int* __restrict__ binBuf, const int* __restrict__ binCur,
    int* __restrict__ ptr, int* __restrict__ srows,
    const unsigned short* __restrict__ xb,
    const unsigned short* __restrict__ wcatT,
    const float* __restrict__ bias,
    unsigned short* __restrict__ xab)
{
    __shared__ __align__(16) unsigned char smem[70656];
    const int bx = blockIdx.x;
    const int tid = threadIdx.x;

    if (bx < NBIN) {
        // ---- binB: per-bin LDS counting sort -> ptr + srows ----
        unsigned int* recs = reinterpret_cast<unsigned int*>(smem);            // 32KB
        int* stage = reinterpret_cast<int*>(smem + 32768);                     // 32KB
        int* boff  = reinterpret_cast<int*>(smem + 65536);                     // 4KB
        int* sred  = reinterpret_cast<int*>(smem + 69632);                     // 1KB
        const int b = bx;
        const int cntb = min(binCur[b], BIN_CAP);

        for (int i = tid; i < cntb; i += 256)
            recs[i] = binBuf[(size_t)b * BIN_CAP + i];

        int myv = (tid < NBIN && tid < b) ? binCur[tid] : 0;
        sred[tid] = myv;
        __syncthreads();
        #pragma unroll
        for (int d = 128; d > 0; d >>= 1) {
            if (tid < d) sred[tid] += sred[tid + d];
            __syncthreads();
        }
        const int binBase = sred[0];
        __syncthreads();

        for (int k = tid; k < 1024; k += 256) boff[k] = 0;
        __syncthreads();
        for (int i = tid; i < cntb; i += 256)
            atomicAdd(&boff[(recs[i] >> 19) & 1023], 1);
        __syncthreads();

        const int c0 = boff[tid * 4], c1 = boff[tid * 4 + 1], c2 = boff[tid * 4 + 2], c3 = boff[tid * 4 + 3];
        const int ts = c0 + c1 + c2 + c3;
        sred[tid] = ts;
        __syncthreads();
        #pragma unroll
        for (int d = 1; d < 256; d <<= 1) {
            int add = (tid >= d) ? sred[tid - d] : 0;
            __syncthreads();
            sred[tid] += add;
            __syncthreads();
        }
        const int run = sred[tid] - ts;
        const int o0 = run, o1 = run + c0, o2 = run + c0 + c1, o3 = run + c0 + c1 + c2;
        boff[tid * 4 + 0] = o0; boff[tid * 4 + 1] = o1;
        boff[tid * 4 + 2] = o2; boff[tid * 4 + 3] = o3;
        const int gb = b * 1024 + tid * 4;
        if (gb + 3 < N_BUCKETS) {
            int4 pv; pv.x = binBase + o0; pv.y = binBase + o1; pv.z = binBase + o2; pv.w = binBase + o3;
            *reinterpret_cast<int4*>(ptr + gb) = pv;
        } else {
            if (gb + 0 < N_BUCKETS) ptr[gb + 0] = binBase + o0;
            if (gb + 1 < N_BUCKETS) ptr[gb + 1] = binBase + o1;
            if (gb + 2 < N_BUCKETS) ptr[gb + 2] = binBase + o2;
            if (gb + 3 < N_BUCKETS) ptr[gb + 3] = binBase + o3;
        }
        if (b == 0 && tid == 0) ptr[N_BUCKETS] = N_EDGES;
        __syncthreads();

        for (int i = tid; i < cntb; i += 256) {
            unsigned int r = recs[i];
            int pos = atomicAdd(&boff[(r >> 19) & 1023], 1);
            stage[pos] = (int)(r & 0x7FFFFu);
        }
        __syncthreads();
        for (int i = tid; i < cntb; i += 256)
            srows[binBase + i] = stage[i];
        return;
    }

    // ---- gemm1 (round-11 form): one jt slab per block ----
    {
        const int gbk = bx - NBIN;
        const int nb = (gbk % G1_NX) * 128;
        const int jt = gbk / G1_NX;

        unsigned short* sX = reinterpret_cast<unsigned short*>(smem);            // [128*136] 34816B
        unsigned short* sW = reinterpret_cast<unsigned short*>(smem + 34816);    // [4*128*32] 32768B

        const int lane = tid & 63;
        const int w = tid >> 6;
        const int g = lane >> 4;
        const int c = lane & 15;
        const int wf = w >> 1;   // j half
        const int we = w & 1;    // n half

        #pragma unroll
        for (int it = 0; it < 8; ++it) {
            int row = 16 * it + (tid >> 4);
            int node = min(nb + row, N_NODES - 1);
            const u16x8 v = *reinterpret_cast<const u16x8*>(xb + (size_t)node * D_IN + (tid & 15) * 8);
            *reinterpret_cast<u16x8*>(&sX[row * 136 + (tid & 15) * 8]) = v;
        }
        {
            const u16x8* gsrc = reinterpret_cast<const u16x8*>(wcatT + (size_t)jt * 16384);
            u16x8* ldst = reinterpret_cast<u16x8*>(sW);
            #pragma unroll
            for (int it = 0; it < 8; ++it)
                ldst[tid + 256 * it] = gsrc[tid + 256 * it];
        }

        f32x4 acc[4][4];
        #pragma unroll
        for (int ft = 0; ft < 4; ++ft)
            #pragma unroll
            for (int et = 0; et < 4; ++et)
                acc[ft][et] = f32x4{0.f, 0.f, 0.f, 0.f};

        __syncthreads();

        #pragma unroll
        for (int ks = 0; ks < 4; ++ks) {
            bf16x8 af[4], bfr[4];
            #pragma unroll
            for (int ft = 0; ft < 4; ++ft)
                af[ft] = *reinterpret_cast<const bf16x8*>(&sW[ks * 4096 + (64 * wf + 16 * ft + c) * 32 + 8 * g]);
            #pragma unroll
            for (int et = 0; et < 4; ++et)
                bfr[et] = *reinterpret_cast<const bf16x8*>(&sX[(64 * we + 16 * et + c) * 136 + ks * 32 + 8 * g]);
            #pragma unroll
            for (int ft = 0; ft < 4; ++ft)
                #pragma unroll
                for (int et = 0; et < 4; ++et)
                    acc[ft][et] = __builtin_amdgcn_mfma_f32_16x16x32_bf16(af[ft], bfr[et], acc[ft][et], 0, 0, 0);
        }
        __syncthreads();   // sX reads done; reuse as output tile

        {
            float bv[4][4];
            #pragma unroll
            for (int ft = 0; ft < 4; ++ft)
                #pragma unroll
                for (int r = 0; r < 4; ++r)
                    bv[ft][r] = bias[jt * 128 + 64 * wf + 16 * ft + 4 * g + r];
            unsigned int* so = reinterpret_cast<unsigned int*>(sX);
            #pragma unroll
            for (int ft = 0; ft < 4; ++ft) {
                #pragma unroll
                for (int et = 0; et < 4; ++et) {
                    int n = 64 * we + 16 * et + c;
                    int jb = 32 * wf + 8 * ft + 2 * g;
                    float v0 = acc[ft][et][0] + bv[ft][0];
                    float v1 = acc[ft][et][1] + bv[ft][1];
                    float v2 = acc[ft][et][2] + bv[ft][2];
                    float v3 = acc[ft][et][3] + bv[ft][3];
                    so[n * 68 + jb + 0] = (unsigned int)f2bf(v0) | ((unsigned int)f2bf(v1) << 16);
                    so[n * 68 + jb + 1] = (unsigned int)f2bf(v2) | ((unsigned int)f2bf(v3) << 16);
                }
            }
        }
        __syncthreads();

        #pragma unroll
        for (int it = 0; it < 8; ++it) {
            int row = 16 * it + (tid >> 4);
            int node = nb + row;
            if (node < N_NODES) {
                const u16x8 v = *reinterpret_cast<const u16x8*>(&sX[row * 136 + (tid & 15) * 8]);
                *reinterpret_cast<u16x8*>(xab + ((size_t)jt * N_NODES + node) * 128 + (tid & 15) * 8) = v;
            }
        }
    }
}

// ---------------- node-major aggregation: one wave per node, scalar control plane ----------------
// One coalesced chunk load of <=64 edge rows per node, then per-edge v_readlane (no per-edge VMEM).
__global__ __launch_bounds__(256) void k_agg(const unsigned short* __restrict__ xab,
                                             const int* __restrict__ ptr,
                                             const int* __restrict__ srows,
                                             unsigned short* __restrict__ S)
{
    const int n = (blockIdx.x * 256 + threadIdx.x) >> 6;   // node = global wave id
    if (n >= N_NODES) return;
    const int lane = threadIdx.x & 63;
    const unsigned int* x32 = reinterpret_cast<const unsigned int*>(xab);

    int seg[5];
    #pragma unroll
    for (int t = 0; t < 5; ++t)
        seg[t] = __builtin_amdgcn_readfirstlane(ptr[4 * n + t]);

    float xbl[4], xbh[4];
    #pragma unroll
    for (int t = 0; t < 4; ++t) {
        unsigned int v = x32[((size_t)(2 * t + 1) * N_NODES + n) * 64 + lane];
        xbl[t] = bf2f_lo(v); xbh[t] = bf2f_hi(v);
    }

    float al[4] = {0.f, 0.f, 0.f, 0.f}, ah[4] = {0.f, 0.f, 0.f, 0.f};

    const int p0 = seg[0], pE = seg[4];
    for (int co = p0; co < pE; co += 64) {
        const int rem = pE - co;
        const int cv = srows[co + min(lane, rem - 1)];   // one coalesced load covers the chunk
        const int ce = min(co + 64, pE);
        #pragma unroll
        for (int t = 0; t < 4; ++t) {
            const int lo = max(seg[t], co);
            const int hi = min(seg[t + 1], ce);
            int j = lo;
            for (; j + 4 <= hi; j += 4) {
                int a0 = __builtin_amdgcn_readlane(cv, j - co);
                int a1 = __builtin_amdgcn_readlane(cv, j + 1 - co);
                int a2 = __builtin_amdgcn_readlane(cv, j + 2 - co);
                int a3 = __builtin_amdgcn_readlane(cv, j + 3 - co);
                unsigned int v0 = x32[(size_t)a0 * 64 + lane];
                unsigned int v1 = x32[(size_t)a1 * 64 + lane];
                unsigned int v2 = x32[(size_t)a2 * 64 + lane];
                unsigned int v3 = x32[(size_t)a3 * 64 + lane];
                al[t] += fmaxf(bf2f_lo(v0) + xbl[t], 0.f) + fmaxf(bf2f_lo(v1) + xbl[t], 0.f)
                       + fmaxf(bf2f_lo(v2) + xbl[t], 0.f) + fmaxf(bf2f_lo(v3) + xbl[t], 0.f);
                ah[t] += fmaxf(bf2f_hi(v0) + xbh[t], 0.f) + fmaxf(bf2f_hi(v1) + xbh[t], 0.f)
                       + fmaxf(bf2f_hi(v2) + xbh[t], 0.f) + fmaxf(bf2f_hi(v3) + xbh[t], 0.f);
            }
            for (; j < hi; ++j) {
                int a = __builtin_amdgcn_readlane(cv, j - co);
                unsigned int v = x32[(size_t)a * 64 + lane];
                al[t] += fmaxf(bf2f_lo(v) + xbl[t], 0.f);
                ah[t] += fmaxf(bf2f_hi(v) + xbh[t], 0.f);
            }
        }
    }

    unsigned int* S32 = reinterpret_cast<unsigned int*>(S);
    #pragma unroll
    for (int t = 0; t < 4; ++t)
        S32[((size_t)n * 4 + t) * 64 + lane] =
            (unsigned int)f2bf(al[t]) | ((unsigned int)f2bf(ah[t]) << 16);
}

// ---------------- GEMM2 (+self-proj) + ReLU + LayerNorm fused, issue-after-barrier staging ----------------
__global__ __launch_bounds__(256, 2) void k_gemm2_ln(
    const unsigned short* __restrict__ S,      // node-major [n][4][128]
    const unsigned short* __restrict__ w2T,
    const unsigned short* __restrict__ wcatT,   // slab 8 = self weights
    const unsigned short* __restrict__ xb,
    const float* __restrict__ b2,
    const float* __restrict__ sb,
    const int* __restrict__ ptr,                // counts via diffs
    const float* __restrict__ gamma,
    const float* __restrict__ beta,
    float* __restrict__ out)
{
    const int nb = blockIdx.x * 128;
    __shared__ __align__(16) unsigned char sm[128 * 136 * 2 + 4 * 128 * 32 * 2 + 512 * 4];
    unsigned short* sS  = reinterpret_cast<unsigned short*>(sm);               // [128*136]
    unsigned short* sW2 = reinterpret_cast<unsigned short*>(sm + 34816);       // [4*128*32]
    float* sB2          = reinterpret_cast<float*>(sm + 34816 + 32768);        // [512]
    float* rows         = reinterpret_cast<float*>(sm);                        // [128][132] alias, post-MFMA

    const int tid = threadIdx.x;
    const int lane = tid & 63;
    const int w = tid >> 6;
    const int g = lane >> 4;
    const int c = lane & 15;
    const int wf = w >> 1;   // f half
    const int we = w & 1;    // n half

    sB2[tid] = b2[tid];
    sB2[tid + 256] = b2[tid + 256];

    f32x4 acc[4][4];
    #pragma unroll
    for (int ft = 0; ft < 4; ++ft)
        #pragma unroll
        for (int et = 0; et < 4; ++et)
            acc[ft][et] = f32x4{0.f, 0.f, 0.f, 0.f};

    // prologue: phase-0 sources into registers
    u16x8 sreg[8], wreg[8];
    {
        #pragma unroll
        for (int it = 0; it < 8; ++it) {
            int row = 16 * it + (tid >> 4);
            int node = min(nb + row, N_NODES - 1);
            sreg[it] = *reinterpret_cast<const u16x8*>(S + ((size_t)node * 4 + 0) * 128 + (tid & 15) * 8);
        }
        const u16x8* gsrc = reinterpret_cast<const u16x8*>(w2T);
        #pragma unroll
        for (int it = 0; it < 8; ++it)
            wreg[it] = gsrc[it * 256 + tid];
    }

    for (int t = 0; t < 5; ++t) {
        // ds_write current phase's tiles (regs already loaded)
        #pragma unroll
        for (int it = 0; it < 8; ++it) {
            int row = 16 * it + (tid >> 4);
            *reinterpret_cast<u16x8*>(&sS[row * 136 + (tid & 15) * 8]) = sreg[it];
        }
        {
            u16x8* ldst = reinterpret_cast<u16x8*>(sW2);
            #pragma unroll
            for (int it = 0; it < 8; ++it)
                ldst[tid + 256 * it] = wreg[it];
        }
        __syncthreads();   // tiles visible

        // issue next phase's loads; they drain at the phase-end barrier (under MFMA)
        if (t < 4) {
            #pragma unroll
            for (int it = 0; it < 8; ++it) {
                int row = 16 * it + (tid >> 4);
                int node = min(nb + row, N_NODES - 1);
                const unsigned short* src = (t + 1 < 4)
                    ? S + ((size_t)node * 4 + (t + 1)) * 128
                    : xb + (size_t)node * 128;
                sreg[it] = *reinterpret_cast<const u16x8*>(src + (tid & 15) * 8);
            }
            const unsigned short* srcW = (t + 1 < 4) ? w2T + (size_t)(t + 1) * 16384
                                                     : wcatT + (size_t)8 * 16384;
            const u16x8* gsrc = reinterpret_cast<const u16x8*>(srcW);
            #pragma unroll
            for (int it = 0; it < 8; ++it)
                wreg[it] = gsrc[it * 256 + tid];
        }
        #pragma unroll
        for (int ks = 0; ks < 4; ++ks) {
            bf16x8 af[4], bfr[4];
            #pragma unroll
            for (int ft = 0; ft < 4; ++ft)
                af[ft] = *reinterpret_cast<const bf16x8*>(&sW2[ks * 4096 + (64 * wf + 16 * ft + c) * 32 + 8 * g]);
            #pragma unroll
            for (int et = 0; et < 4; ++et)
                bfr[et] = *reinterpret_cast<const bf16x8*>(&sS[(64 * we + 16 * et + c) * 136 + ks * 32 + 8 * g]);
            #pragma unroll
            for (int ft = 0; ft < 4; ++ft)
                #pragma unroll
                for (int et = 0; et < 4; ++et)
                    acc[ft][et] = __builtin_amdgcn_mfma_f32_16x16x32_bf16(af[ft], bfr[et], acc[ft][et], 0, 0, 0);
        }
        __syncthreads();   // drains next-phase loads; MFMA reads done before next ds_write / rows[] alias
    }

    #pragma unroll
    for (int et = 0; et < 4; ++et) {
        int n = 64 * we + 16 * et + c;
        int node = nb + n;
        if (node >= N_NODES) continue;
        const int4 pv4 = *reinterpret_cast<const int4*>(ptr + node * 4);
        const int pe = ptr[node * 4 + 4];
        float cnt4[N_TYPES] = {(float)(pv4.y - pv4.x), (float)(pv4.z - pv4.y),
                               (float)(pv4.w - pv4.z), (float)(pe - pv4.w)};
        #pragma unroll
        for (int ft = 0; ft < 4; ++ft) {
            int f0 = 64 * wf + 16 * ft + 4 * g;
            const float4 sbv = *reinterpret_cast<const float4*>(sb + f0);
            float v[4];
            v[0] = acc[ft][et][0] + sbv.x;
            v[1] = acc[ft][et][1] + sbv.y;
            v[2] = acc[ft][et][2] + sbv.z;
            v[3] = acc[ft][et][3] + sbv.w;
            #pragma unroll
            for (int r = 0; r < 4; ++r) {
                float bs = 0.f;
                #pragma unroll
                for (int t = 0; t < N_TYPES; ++t)
                    bs = fmaf(cnt4[t], sB2[t * 128 + f0 + r], bs);
                v[r] += bs;
            }
            *reinterpret_cast<float4*>(&rows[n * 132 + f0]) = *reinterpret_cast<float4*>(v);
        }
    }
    __syncthreads();

    for (int rr = 0; rr < 32; ++rr) {
        int r = w * 32 + rr;
        int node = nb + r;
        if (node >= N_NODES) break;
        float2 v = *reinterpret_cast<float2*>(&rows[r * 132 + lane * 2]);
        v.x = fmaxf(v.x, 0.f);
        v.y = fmaxf(v.y, 0.f);
        float s = v.x + v.y;
        float ss = v.x * v.x + v.y * v.y;
        #pragma unroll
        for (int m = 1; m < 64; m <<= 1) {
            s  += __shfl_xor(s, m, 64);
            ss += __shfl_xor(ss, m, 64);
        }
        float mu = s * (1.f / 128.f);
        float var = ss * (1.f / 128.f) - mu * mu;
        float rs = rsqrtf(var + LN_EPS);
        const float2 gm = *reinterpret_cast<const float2*>(gamma + lane * 2);
        const float2 bt = *reinterpret_cast<const float2*>(beta + lane * 2);
        float2 o;
        o.x = (v.x - mu) * rs * gm.x + bt.x;
        o.y = (v.y - mu) * rs * gm.y + bt.y;
        *reinterpret_cast<float2*>(out + (size_t)node * D_OUT + lane * 2) = o;
    }
}

extern "C" void kernel_launch(void* const* d_in, const int* in_sizes, int n_in,
                              void* d_out, int out_size, void* d_ws, size_t ws_size,
                              hipStream_t stream) {
    const float* x     = (const float*)d_in[0];
    const int*   ei    = (const int*)d_in[1];
    const int*   attr  = (const int*)d_in[2];
    const float* w1    = (const float*)d_in[3];
    const float* b1    = (const float*)d_in[4];
    const float* w2    = (const float*)d_in[5];
    const float* b2    = (const float*)d_in[6];
    const float* sw    = (const float*)d_in[7];
    const float* sb    = (const float*)d_in[8];
    const float* gamma = (const float*)d_in[9];
    const float* beta  = (const float*)d_in[10];
    float* out = (float*)d_out;

    if (ws_size < WS_TOTAL) return;   // fail visibly rather than corrupt

    char* ws = (char*)d_ws;
    int* ptr    = (int*)(ws + OFF_PTR);
    int* binCur = (int*)(ws + OFF_BCUR);
    unsigned int* binBuf = (unsigned int*)(ws + OFF_BINBUF);
    int* srows  = (int*)(ws + OFF_SROWS);
    unsigned short* xb    = (unsigned short*)(ws + OFF_XB);
    unsigned short* wcatT = (unsigned short*)(ws + OFF_WCAT);
    float*          bias  = (float*)(ws + OFF_BIAS);
    unsigned short* w2T   = (unsigned short*)(ws + OFF_W2T);
    unsigned short* xab   = (unsigned short*)(ws + OFF_XAB);
    unsigned short* S     = (unsigned short*)(ws + OFF_S);

    hipMemsetAsync(binCur, 0, (size_t)NBIN * 4, stream);

    k_prep_binA<<<NBA + NB_CVT + NB_PREP, 256, 0, stream>>>(
        x, w1, sw, b1, sb, w2, ei, attr, xb, wcatT, bias, w2T, binCur, binBuf);

    k_binB_gemm1<<<NBIN + G1_NX * 8, 256, 0, stream>>>(
        binBuf, binCur, ptr, srows, xb, wcatT, bias, xab);

    k_agg<<<(N_NODES * 64 + 255) / 256, 256, 0, stream>>>(xab, ptr, srows, S);
    k_gemm2_ln<<<(N_NODES + 127) / 128, 256, 0, stream>>>(
        S, w2T, wcatT, xb, b2, sb, ptr, gamma, beta, out);
}